// Round 10
// baseline (269.155 us; speedup 1.0000x reference)
//
#include <hip/hip_runtime.h>
#include <hip/hip_bf16.h>

#define DIM 128

typedef __attribute__((ext_vector_type(8))) short bf16x8;
typedef __attribute__((ext_vector_type(4))) float f32x4;

// ---- ws layout (float offsets) ----
#define WS_B12    0        // 128
#define WS_C      128      // 128  (unused; layout stability)
#define WS_SUMEE  256      // 128
#define WS_S      384      // 1
#define WS_ZB     416      // 64   Z buckets (atomic, 64-way)
#define WS_GEB    512      // 32*128 ge buckets (atomic, 32-way)
#define WS_WBF    4608     // 32768 bf16: Wcat[n][k]
#define WS_EEP    20992    // 128*1024 sum_eE partials
#define WS_SEP    152064   // 1024 S partials
#define WS_SP     153088   // N
#define WS_E      415232   // N
#define WS_WEXP   677376   // N
#define WS_EBF    939520   // N*136 bf16 PADDED rows (=17,825,792 floats, 71.3 MB)
// EBF row stride = 136 shorts (272 B): global layout == k4's LDS layout, so
// global_load_lds's linear wave-fill reproduces the bank-conflict-free tile.

__device__ __forceinline__ unsigned short f2bf(float f) {
    union { float f; unsigned u; } v; v.f = f;
    unsigned r = v.u + 0x7fffu + ((v.u >> 16) & 1u);
    return (unsigned short)(r >> 16);
}

__device__ __forceinline__ float bfbits(unsigned u) {
    union { unsigned u; float f; } v; v.u = u;
    return v.f;
}

__device__ __forceinline__ unsigned pkbf(float a, float b) {
    union { __hip_bfloat162 h; unsigned u; } cv;
    cv.h = __float22bfloat162_rn(make_float2(a, b));
    return cv.u;
}

// ---------------- K2: one pass over E -> sp, e, bf16(E) padded, per-block partials ----------------
__global__ __launch_bounds__(256) void k2_stats(const float* __restrict__ E,
                                                const float* __restrict__ v,
                                                const float* __restrict__ wpa,
                                                const float* __restrict__ bpa,
                                                const float* __restrict__ Wc1,
                                                const float* __restrict__ Wc2,
                                                const float* __restrict__ bc1,
                                                const float* __restrict__ bc2,
                                                float* __restrict__ ws) {
    __shared__ float red[16][128];
    __shared__ float redS[16];
    int t = threadIdx.x;

    // ---- folded k1: weight conversion + bucket zero-init
    int gid = blockIdx.x * 256 + t;
    unsigned short* wbf_w = (unsigned short*)(ws + WS_WBF);
    if (gid < 32768) {
        int n = gid >> 7, k = gid & 127;
        float val = (n < 128) ? Wc1[n * 128 + k] : Wc2[(n - 128) * 128 + k];
        wbf_w[gid] = f2bf(val);
    }
    if (gid < 4096) ws[WS_GEB + gid] = 0.f;
    if (gid < 128) ws[WS_B12 + gid] = bc1[gid] + bc2[gid];
    if (gid < 64) ws[WS_ZB + gid] = 0.f;

    int wave = t >> 6, lane = t & 63;
    int cl = lane & 15, rs = lane >> 4;
    int row0 = blockIdx.x * 256;
    const float4* E4 = (const float4*)E;
    unsigned short* ebf = (unsigned short*)(ws + WS_EBF);

    float4 va = ((const float4*)v)[cl];
    float4 vb = ((const float4*)v)[16 + cl];
    float4 pa = ((const float4*)wpa)[cl];
    float4 pb = ((const float4*)wpa)[16 + cl];
    float bias = bpa[0];

    float4 acc0 = {0.f, 0.f, 0.f, 0.f}, acc1 = {0.f, 0.f, 0.f, 0.f};
    float se = 0.f;
    float* sp_ws = ws + WS_SP;
    float* e_ws = ws + WS_E;

#pragma unroll 8
    for (int it = 0; it < 16; ++it) {
        int row = row0 + it * 16 + wave * 4 + rs;
        float4 x0 = E4[row * 32 + cl];
        float4 x1 = E4[row * 32 + 16 + cl];
        unsigned p0 = pkbf(x0.x, x0.y);
        unsigned p1 = pkbf(x0.z, x0.w);
        unsigned p2 = pkbf(x1.x, x1.y);
        unsigned p3 = pkbf(x1.z, x1.w);
        // padded 136-short row stride (8B-aligned: 272*row + 8*cl)
        *(uint2*)(ebf + (size_t)row * 136 + cl * 4) = make_uint2(p0, p1);
        *(uint2*)(ebf + (size_t)row * 136 + 64 + cl * 4) = make_uint2(p2, p3);

        float dv = x0.x * va.x + x0.y * va.y + x0.z * va.z + x0.w * va.w
                 + x1.x * vb.x + x1.y * vb.y + x1.z * vb.z + x1.w * vb.w;
        float dp = x0.x * pa.x + x0.y * pa.y + x0.z * pa.z + x0.w * pa.w
                 + x1.x * pb.x + x1.y * pb.y + x1.z * pb.z + x1.w * pb.w;
        for (int off = 1; off < 16; off <<= 1) {
            dv += __shfl_xor(dv, off);
            dp += __shfl_xor(dp, off);
        }
        float e = __expf(dp + bias);
        if (cl == 0) {
            sp_ws[row] = dv;
            e_ws[row] = e;
            se += e;
        }
        acc0.x += e * x0.x; acc0.y += e * x0.y; acc0.z += e * x0.z; acc0.w += e * x0.w;
        acc1.x += e * x1.x; acc1.y += e * x1.y; acc1.z += e * x1.z; acc1.w += e * x1.w;
    }
    int rr = wave * 4 + rs;
    float* dst = red[rr];
    dst[cl * 4 + 0] = acc0.x; dst[cl * 4 + 1] = acc0.y;
    dst[cl * 4 + 2] = acc0.z; dst[cl * 4 + 3] = acc0.w;
    dst[64 + cl * 4 + 0] = acc1.x; dst[64 + cl * 4 + 1] = acc1.y;
    dst[64 + cl * 4 + 2] = acc1.z; dst[64 + cl * 4 + 3] = acc1.w;
    if (cl == 0) redS[rr] = se;
    __syncthreads();
    if (t < 128) {
        float s = 0.f;
#pragma unroll
        for (int r = 0; r < 16; ++r) s += red[r][t];
        ws[WS_EEP + t * 1024 + blockIdx.x] = s;
    }
    if (t == 0) {
        float s = 0.f;
#pragma unroll
        for (int r = 0; r < 16; ++r) s += redS[r];
        ws[WS_SEP + blockIdx.x] = s;
    }
}

// ---------------- K2b: reduce partials -> SUMEE[128], S ----------------
__global__ __launch_bounds__(256) void k2b_reduce(float* __restrict__ ws) {
    __shared__ float r4[4];
    int t = threadIdx.x, blk = blockIdx.x;
    const float* src = (blk < 128) ? (ws + WS_EEP + blk * 1024) : (ws + WS_SEP);
    float s = src[t] + src[t + 256] + src[t + 512] + src[t + 768];
    for (int off = 1; off < 64; off <<= 1) s += __shfl_xor(s, off);
    if ((t & 63) == 0) r4[t >> 6] = s;
    __syncthreads();
    if (t == 0) {
        float tot = r4[0] + r4[1] + r4[2] + r4[3];
        if (blk < 128) ws[WS_SUMEE + blk] = tot;
        else ws[WS_S] = tot;
    }
}

// ---------------- K4: 4-wave transposed MFMA GEMM, global_load_lds staging ----------------
// 1024 blocks x 256 thr, 4 tiles/block. Staging via __builtin_amdgcn_global_load_lds
// (16B width) from the PADDED bf16 copy: frees 16 staging VGPRs and removes all
// ds_write traffic. Per-rt accumulators (epilogue inside rt loop): acc live regs
// 64 -> 16. Target VGPR ~130-150 under __launch_bounds__(256,3) => 12-16 waves/CU
// (r8/r9 ran at 8 — occupancy was eating ~40% of each predicted pipe win).
// Triple-buffered Elds; one barrier per tile; same WAR epochs as r8/r9.
__global__ __launch_bounds__(256, 3) void k4_main(const float* __restrict__ wvc,
                                                  const float* __restrict__ bvc_p,
                                                  const float* __restrict__ Wc2,
                                                  float* __restrict__ ws) {
    __shared__ unsigned short Elds[3][64 * 136];   // 3 x 17,408 B = 17 chunks of 1024 B each
    __shared__ __align__(16) float arena[644];
    // loop-phase:  pim2 = arena[0..511] ([2][64][4]); c_lds = arena[512..639]
    // final-phase: gep  = arena[0..511] ([4][128]); zw = arena[640..643]
    float* pim2  = arena;
    float* c_lds = arena + 512;
    float* zw    = arena + 640;
    float* gep_a = arena;

    int t = threadIdx.x;
    int w = t >> 6, lane = t & 63, cl = lane & 15, q = lane >> 4;
    int blk = blockIdx.x;
    int row_base = blk * 256;                    // 4 tiles x 64 rows
    const unsigned short* wbf = (const unsigned short*)(ws + WS_WBF);
    const unsigned short* EbP = (const unsigned short*)(ws + WS_EBF);
    const float* e_ws = ws + WS_E;

    float bvc = bvc_p[0];
    float Sv = ws[WS_S];
    int r0 = w * 16 + q * 4;                     // this lane's 4 rows within a tile

// stage one 17,408-B tile into Elds[buf] via 17 x 1024-B global_load_lds chunks.
// wave w covers chunks {w, w+4, w+8, w+12}; wave 0 also chunk 16.
#define STAGE(buf, trow) do {                                                          \
    const unsigned short* gs_ = EbP + (size_t)(trow) * 136;                            \
    _Pragma("unroll")                                                                  \
    for (int k_ = 0; k_ < 4; ++k_) {                                                   \
        int c_ = w + k_ * 4;                                                           \
        __builtin_amdgcn_global_load_lds(                                              \
            (const __attribute__((address_space(1))) void*)(gs_ + c_ * 512 + lane * 8),\
            (__attribute__((address_space(3))) void*)(&Elds[buf][c_ * 512]),           \
            16, 0, 0);                                                                 \
    }                                                                                  \
    if (w == 0)                                                                        \
        __builtin_amdgcn_global_load_lds(                                              \
            (const __attribute__((address_space(1))) void*)(gs_ + 16 * 512 + lane * 8),\
            (__attribute__((address_space(3))) void*)(&Elds[buf][16 * 512]),           \
            16, 0, 0);                                                                 \
} while (0)

    // A fragments: wave w owns j-tiles {2w, 2w+1} for BOTH W_c1 and W_c2
    bf16x8 aw[2][2][4];   // [jt][0=W1,1=W2][kt]
#pragma unroll
    for (int jt = 0; jt < 2; ++jt) {
#pragma unroll
        for (int kt = 0; kt < 4; ++kt) {
            int jrow = w * 32 + jt * 16 + cl;
            aw[jt][0][kt] = *(const bf16x8*)(wbf + jrow * 128 + kt * 32 + q * 8);
            aw[jt][1][kt] = *(const bf16x8*)(wbf + (128 + jrow) * 128 + kt * 32 + q * 8);
        }
    }

    // per-lane j-row constants: j = w*32 + jt*16 + q*4 + reg
    float b12r[2][4], wvr[2][4];
#pragma unroll
    for (int jt = 0; jt < 2; ++jt)
#pragma unroll
        for (int reg = 0; reg < 4; ++reg) {
            int jr = w * 32 + jt * 16 + q * 4 + reg;
            b12r[jt][reg] = ws[WS_B12 + jr];
            wvr[jt][reg] = wvc[jr];
        }

    // folded k3: c[j] = Wc2[j,:] . sumEE
    if (t < 128) {
        const float4* row = (const float4*)(Wc2 + t * 128);
        const float4* se4 = (const float4*)(ws + WS_SUMEE);
        float4 s4 = {0.f, 0.f, 0.f, 0.f};
#pragma unroll
        for (int k = 0; k < 32; ++k) {
            float4 a = row[k], b = se4[k];
            s4.x += a.x * b.x; s4.y += a.y * b.y; s4.z += a.z * b.z; s4.w += a.w * b.w;
        }
        c_lds[t] = s4.x + s4.y + s4.z + s4.w;
    }

    STAGE(0, row_base);      // tile 0 -> buf 0 (drained by B_pro's vmcnt)
    __syncthreads();         // B_pro: buf0/c_lds visible

    float cjr[2][4];
#pragma unroll
    for (int jt = 0; jt < 2; ++jt)
#pragma unroll
        for (int reg = 0; reg < 4; ++reg)
            cjr[jt][reg] = c_lds[w * 32 + jt * 16 + q * 4 + reg];

    float z_lane = 0.f;
    float acc8[8] = {0.f, 0.f, 0.f, 0.f, 0.f, 0.f, 0.f, 0.f};

    for (int it = 0; it < 4; ++it) {
        int cur = it % 3;
        int pb = it & 1;
        int trow0 = row_base + it * 64;

        // stage tile it+1 -> buf (it+1)%3 (async; drains at this iter's B1)
        if (it < 3) STAGE((it + 1) % 3, trow0 + 64);

        float4 sp4 = *(const float4*)&ws[WS_SP + trow0 + r0];
        float evr[4];
#pragma unroll
        for (int rt = 0; rt < 4; ++rt) evr[rt] = e_ws[trow0 + rt * 16 + cl];

        // per-rt: ds_read b-frags -> 16 MFMA -> epilogue -> pim write (acc 16 regs live)
#pragma unroll
        for (int rt = 0; rt < 4; ++rt) {
            bf16x8 b[4];
#pragma unroll
            for (int kt = 0; kt < 4; ++kt)
                b[kt] = *(const bf16x8*)&Elds[cur][(rt * 16 + cl) * 136 + kt * 32 + q * 8];
            f32x4 a00 = {0.f,0.f,0.f,0.f}, a01 = {0.f,0.f,0.f,0.f};
            f32x4 a10 = {0.f,0.f,0.f,0.f}, a11 = {0.f,0.f,0.f,0.f};
#pragma unroll
            for (int kt = 0; kt < 4; ++kt) {
                a00 = __builtin_amdgcn_mfma_f32_16x16x32_bf16(aw[0][0][kt], b[kt], a00, 0, 0, 0);
                a01 = __builtin_amdgcn_mfma_f32_16x16x32_bf16(aw[0][1][kt], b[kt], a01, 0, 0, 0);
                a10 = __builtin_amdgcn_mfma_f32_16x16x32_bf16(aw[1][0][kt], b[kt], a10, 0, 0, 0);
                a11 = __builtin_amdgcn_mfma_f32_16x16x32_bf16(aw[1][1][kt], b[kt], a11, 0, 0, 0);
            }
            float e_v = evr[rt];
            float di_v = 1.0f / (Sv - e_v);
            float p = 0.f;
#pragma unroll
            for (int reg = 0; reg < 4; ++reg) {       // jt=0 first (order matches r9)
                float h = a00[reg] + b12r[0][reg] + (cjr[0][reg] - e_v * a01[reg]) * di_v;
                p = fmaf(wvr[0][reg], fmaxf(h, 0.f), p);
            }
#pragma unroll
            for (int reg = 0; reg < 4; ++reg) {       // then jt=1
                float h = a10[reg] + b12r[1][reg] + (cjr[1][reg] - e_v * a11[reg]) * di_v;
                p = fmaf(wvr[1][reg], fmaxf(h, 0.f), p);
            }
            p += __shfl_xor(p, 16);
            p += __shfl_xor(p, 32);
            if (lane < 16) pim2[(pb * 64 + rt * 16 + lane) * 4 + w] = p;
        }
        __syncthreads();   // B1: pim[pb] + Elds[(it+1)%3] (vmcnt-drained) visible

        // wexp: 4 rows/lane; one float4 per row
        float we[4];
#pragma unroll
        for (int rr = 0; rr < 4; ++rr) {
            float4 P = *(const float4*)&pim2[(pb * 64 + r0 + rr) * 4];
            float pi = (P.x + P.y) + (P.z + P.w);
            float spv = (rr == 0) ? sp4.x : (rr == 1) ? sp4.y : (rr == 2) ? sp4.z : sp4.w;
            we[rr] = __expf(spv + bvc + pi);
            z_lane += we[rr];
        }
        if (cl == 0)
            *(float4*)&ws[WS_WEXP + trow0 + r0] = (float4){we[0], we[1], we[2], we[3]};

#pragma unroll
        for (int rr = 0; rr < 4; ++rr) {
            int r = r0 + rr;
            float wer = we[rr];
            uint4 u = *(const uint4*)&Elds[cur][r * 136 + cl * 8];
            acc8[0] += wer * bfbits(u.x << 16);
            acc8[1] += wer * bfbits(u.x & 0xffff0000u);
            acc8[2] += wer * bfbits(u.y << 16);
            acc8[3] += wer * bfbits(u.y & 0xffff0000u);
            acc8[4] += wer * bfbits(u.z << 16);
            acc8[5] += wer * bfbits(u.z & 0xffff0000u);
            acc8[6] += wer * bfbits(u.w << 16);
            acc8[7] += wer * bfbits(u.w & 0xffff0000u);
        }
        // no trailing barrier: next iter's STAGE targets buf[(it+2)%3], disjoint from
        // this iter's post-B1 reads of buf[it%3]; pim dbuf covers the pim WAR.
    }
#undef STAGE

    __syncthreads();   // all pim reads done -> arena reusable as gep/zw

    z_lane += __shfl_xor(z_lane, 16);
    z_lane += __shfl_xor(z_lane, 32);
    if (lane == 0) zw[w] = z_lane;

#pragma unroll
    for (int jj = 0; jj < 8; ++jj) {
        acc8[jj] += __shfl_xor(acc8[jj], 16);
        acc8[jj] += __shfl_xor(acc8[jj], 32);
    }
    if (lane < 16) {
        *(float4*)&gep_a[w * 128 + cl * 8] = (float4){acc8[0], acc8[1], acc8[2], acc8[3]};
        *(float4*)&gep_a[w * 128 + cl * 8 + 4] = (float4){acc8[4], acc8[5], acc8[6], acc8[7]};
    }
    __syncthreads();

    if (t < 128) {
        float tot = gep_a[t] + gep_a[128 + t] + gep_a[256 + t] + gep_a[384 + t];
        atomicAdd(&ws[WS_GEB + (blk & 31) * 128 + t], tot);
    }
    if (t == 128) {
        float zs = zw[0] + zw[1] + zw[2] + zw[3];
        atomicAdd(&ws[WS_ZB + (blk & 63)], zs);
    }
}

// ---------------- K5: normalize + write outputs ----------------
__global__ __launch_bounds__(256) void k5_final(const float* __restrict__ ws,
                                                float* __restrict__ out) {
    int t = threadIdx.x, blk = blockIdx.x;
    float z = ws[WS_ZB + (t & 63)];
    for (int off = 1; off < 64; off <<= 1) z += __shfl_xor(z, off);
    float invZ = 1.0f / z;
    if (blk < 1024) {
        int i = blk * 256 + t;
        out[128 + i] = ws[WS_WEXP + i] * invZ;
    } else if (t < 128) {
        float s = 0.f;
#pragma unroll
        for (int b = 0; b < 32; ++b) s += ws[WS_GEB + b * 128 + t];
        out[t] = s * invZ;
    }
}

extern "C" void kernel_launch(void* const* d_in, const int* in_sizes, int n_in,
                              void* d_out, int out_size, void* d_ws, size_t ws_size,
                              hipStream_t stream) {
    const float* E   = (const float*)d_in[0];
    const float* v   = (const float*)d_in[1];
    const float* Wc1 = (const float*)d_in[2];
    const float* bc1 = (const float*)d_in[3];
    const float* Wc2 = (const float*)d_in[4];
    const float* bc2 = (const float*)d_in[5];
    const float* wpa = (const float*)d_in[6];
    const float* bpa = (const float*)d_in[7];
    const float* wvc = (const float*)d_in[8];
    const float* bvc = (const float*)d_in[9];
    float* ws  = (float*)d_ws;
    float* out = (float*)d_out;

    k2_stats<<<1024, 256, 0, stream>>>(E, v, wpa, bpa, Wc1, Wc2, bc1, bc2, ws);
    k2b_reduce<<<129, 256, 0, stream>>>(ws);
    k4_main<<<1024, 256, 0, stream>>>(wvc, bvc, Wc2, ws);
    k5_final<<<1025, 256, 0, stream>>>(ws, out);
}

// Round 11
// 251.420 us; speedup vs baseline: 1.0705x; 1.0705x over previous
//
#include <hip/hip_runtime.h>
#include <hip/hip_bf16.h>

#define DIM 128

typedef __attribute__((ext_vector_type(8))) short bf16x8;
typedef __attribute__((ext_vector_type(4))) float f32x4;

// ---- ws layout (float offsets) ----
#define WS_B12    0        // 128
#define WS_C      128      // 128  (unused; layout stability)
#define WS_SUMEE  256      // 128
#define WS_S      384      // 1
#define WS_ZB     416      // 64   Z buckets (atomic, 64-way)
#define WS_GEB    512      // 32*128 ge buckets (atomic, 32-way)
#define WS_WBF    4608     // 32768 bf16: Wcat[n][k]
#define WS_EEP    20992    // 128*1024 sum_eE partials
#define WS_SEP    152064   // 1024 S partials
#define WS_SP     153088   // N
#define WS_E      415232   // N
#define WS_WEXP   677376   // N
#define WS_EBF    939520   // N*128 bf16 (row-major), 64 MB

__device__ __forceinline__ unsigned short f2bf(float f) {
    union { float f; unsigned u; } v; v.f = f;
    unsigned r = v.u + 0x7fffu + ((v.u >> 16) & 1u);
    return (unsigned short)(r >> 16);
}

__device__ __forceinline__ float bfbits(unsigned u) {
    union { unsigned u; float f; } v; v.u = u;
    return v.f;
}

__device__ __forceinline__ unsigned pkbf(float a, float b) {
    union { __hip_bfloat162 h; unsigned u; } cv;
    cv.h = __float22bfloat162_rn(make_float2(a, b));
    return cv.u;
}

// ---------------- K2: one pass over E -> sp, e, bf16(E), per-block {S, sum_eE} partials ----------------
__global__ __launch_bounds__(256) void k2_stats(const float* __restrict__ E,
                                                const float* __restrict__ v,
                                                const float* __restrict__ wpa,
                                                const float* __restrict__ bpa,
                                                const float* __restrict__ Wc1,
                                                const float* __restrict__ Wc2,
                                                const float* __restrict__ bc1,
                                                const float* __restrict__ bc2,
                                                float* __restrict__ ws) {
    __shared__ float red[16][128];
    __shared__ float redS[16];
    int t = threadIdx.x;

    // ---- folded k1: weight conversion + bucket zero-init
    int gid = blockIdx.x * 256 + t;
    unsigned short* wbf_w = (unsigned short*)(ws + WS_WBF);
    if (gid < 32768) {
        int n = gid >> 7, k = gid & 127;
        float val = (n < 128) ? Wc1[n * 128 + k] : Wc2[(n - 128) * 128 + k];
        wbf_w[gid] = f2bf(val);
    }
    if (gid < 4096) ws[WS_GEB + gid] = 0.f;
    if (gid < 128) ws[WS_B12 + gid] = bc1[gid] + bc2[gid];
    if (gid < 64) ws[WS_ZB + gid] = 0.f;

    int wave = t >> 6, lane = t & 63;
    int cl = lane & 15, rs = lane >> 4;
    int row0 = blockIdx.x * 256;
    const float4* E4 = (const float4*)E;
    unsigned short* ebf = (unsigned short*)(ws + WS_EBF);

    float4 va = ((const float4*)v)[cl];
    float4 vb = ((const float4*)v)[16 + cl];
    float4 pa = ((const float4*)wpa)[cl];
    float4 pb = ((const float4*)wpa)[16 + cl];
    float bias = bpa[0];

    float4 acc0 = {0.f, 0.f, 0.f, 0.f}, acc1 = {0.f, 0.f, 0.f, 0.f};
    float se = 0.f;
    float* sp_ws = ws + WS_SP;
    float* e_ws = ws + WS_E;

#pragma unroll 8
    for (int it = 0; it < 16; ++it) {
        int row = row0 + it * 16 + wave * 4 + rs;
        float4 x0 = E4[row * 32 + cl];
        float4 x1 = E4[row * 32 + 16 + cl];
        unsigned p0 = pkbf(x0.x, x0.y);
        unsigned p1 = pkbf(x0.z, x0.w);
        unsigned p2 = pkbf(x1.x, x1.y);
        unsigned p3 = pkbf(x1.z, x1.w);
        *(uint2*)(ebf + (size_t)row * 128 + cl * 4) = make_uint2(p0, p1);
        *(uint2*)(ebf + (size_t)row * 128 + 64 + cl * 4) = make_uint2(p2, p3);

        float dv = x0.x * va.x + x0.y * va.y + x0.z * va.z + x0.w * va.w
                 + x1.x * vb.x + x1.y * vb.y + x1.z * vb.z + x1.w * vb.w;
        float dp = x0.x * pa.x + x0.y * pa.y + x0.z * pa.z + x0.w * pa.w
                 + x1.x * pb.x + x1.y * pb.y + x1.z * pb.z + x1.w * pb.w;
        for (int off = 1; off < 16; off <<= 1) {
            dv += __shfl_xor(dv, off);
            dp += __shfl_xor(dp, off);
        }
        float e = __expf(dp + bias);
        if (cl == 0) {
            sp_ws[row] = dv;
            e_ws[row] = e;
            se += e;
        }
        acc0.x += e * x0.x; acc0.y += e * x0.y; acc0.z += e * x0.z; acc0.w += e * x0.w;
        acc1.x += e * x1.x; acc1.y += e * x1.y; acc1.z += e * x1.z; acc1.w += e * x1.w;
    }
    int rr = wave * 4 + rs;
    float* dst = red[rr];
    dst[cl * 4 + 0] = acc0.x; dst[cl * 4 + 1] = acc0.y;
    dst[cl * 4 + 2] = acc0.z; dst[cl * 4 + 3] = acc0.w;
    dst[64 + cl * 4 + 0] = acc1.x; dst[64 + cl * 4 + 1] = acc1.y;
    dst[64 + cl * 4 + 2] = acc1.z; dst[64 + cl * 4 + 3] = acc1.w;
    if (cl == 0) redS[rr] = se;
    __syncthreads();
    if (t < 128) {
        float s = 0.f;
#pragma unroll
        for (int r = 0; r < 16; ++r) s += red[r][t];
        ws[WS_EEP + t * 1024 + blockIdx.x] = s;
    }
    if (t == 0) {
        float s = 0.f;
#pragma unroll
        for (int r = 0; r < 16; ++r) s += redS[r];
        ws[WS_SEP + blockIdx.x] = s;
    }
}

// ---------------- K2b: reduce partials -> SUMEE[128], S ----------------
__global__ __launch_bounds__(256) void k2b_reduce(float* __restrict__ ws) {
    __shared__ float r4[4];
    int t = threadIdx.x, blk = blockIdx.x;
    const float* src = (blk < 128) ? (ws + WS_EEP + blk * 1024) : (ws + WS_SEP);
    float s = src[t] + src[t + 256] + src[t + 512] + src[t + 768];
    for (int off = 1; off < 64; off <<= 1) s += __shfl_xor(s, off);
    if ((t & 63) == 0) r4[t >> 6] = s;
    __syncthreads();
    if (t == 0) {
        float tot = r4[0] + r4[1] + r4[2] + r4[3];
        if (blk < 128) ws[WS_SUMEE + blk] = tot;
        else ws[WS_S] = tot;
    }
}

// ---------------- K4: 4-wave transposed MFMA GEMM, 8 tiles/block, 1 barrier/tile ----------------
// REVERT to r9's reg-staged structure (r10 lesson: global_load_lds forces vmcnt(0)
// drain at every barrier -> stage latency fully exposed; reg-staging keeps loads in
// private VGPRs across barriers, vmcnt wait lands at next iter's ds_write = 1 full
// iteration of slack). Kept from r10: per-rt accumulators (epilogue inside rt loop,
// 16 live acc VGPRs vs 64; identical p-accumulation order) -> peak VGPR ~230->~190,
// more scheduler headroom to hoist sN loads / b-frag ds_reads.
__global__ __launch_bounds__(256, 2) void k4_main(const float* __restrict__ wvc,
                                                  const float* __restrict__ bvc_p,
                                                  const float* __restrict__ Wc2,
                                                  float* __restrict__ ws) {
    __shared__ unsigned short Elds[3][64 * 136];   // 3 x 17,408 B
    __shared__ __align__(16) float arena[644];
    // loop-phase:  pim2 = arena[0..511] ([2][64][4]); c_lds = arena[512..639]
    // final-phase: gep  = arena[0..511] ([4][128]); zw = arena[640..643]
    float* pim2  = arena;
    float* c_lds = arena + 512;
    float* zw    = arena + 640;
    float* gep_a = arena;

    int t = threadIdx.x;
    int w = t >> 6, lane = t & 63, cl = lane & 15, q = lane >> 4;
    int blk = blockIdx.x;
    int row_base = blk * 512;                    // 8 tiles x 64 rows
    const unsigned short* wbf = (const unsigned short*)(ws + WS_WBF);
    const unsigned short* EbBase = (const unsigned short*)(ws + WS_EBF);
    const float* e_ws = ws + WS_E;

    float bvc = bvc_p[0];
    float Sv = ws[WS_S];
    int r0 = w * 16 + q * 4;                     // this lane's 4 rows within a tile
    int sr0 = t >> 4,           sc0 = t & 15;
    int sr1 = (t + 256) >> 4,   sc1 = (t + 256) & 15;
    int sr2 = (t + 512) >> 4,   sc2 = (t + 512) & 15;
    int sr3 = (t + 768) >> 4,   sc3 = (t + 768) & 15;

    // A fragments: wave w owns j-tiles {2w, 2w+1} for BOTH W_c1 and W_c2
    bf16x8 aw[2][2][4];   // [jt][0=W1,1=W2][kt]
#pragma unroll
    for (int jt = 0; jt < 2; ++jt) {
#pragma unroll
        for (int kt = 0; kt < 4; ++kt) {
            int jrow = w * 32 + jt * 16 + cl;
            aw[jt][0][kt] = *(const bf16x8*)(wbf + jrow * 128 + kt * 32 + q * 8);
            aw[jt][1][kt] = *(const bf16x8*)(wbf + (128 + jrow) * 128 + kt * 32 + q * 8);
        }
    }

    // per-lane j-row constants: j = w*32 + jt*16 + q*4 + reg
    float b12r[2][4], wvr[2][4];
#pragma unroll
    for (int jt = 0; jt < 2; ++jt)
#pragma unroll
        for (int reg = 0; reg < 4; ++reg) {
            int jr = w * 32 + jt * 16 + q * 4 + reg;
            b12r[jt][reg] = ws[WS_B12 + jr];
            wvr[jt][reg] = wvc[jr];
        }

    // folded k3: c[j] = Wc2[j,:] . sumEE
    if (t < 128) {
        const float4* row = (const float4*)(Wc2 + t * 128);
        const float4* se4 = (const float4*)(ws + WS_SUMEE);
        float4 s4 = {0.f, 0.f, 0.f, 0.f};
#pragma unroll
        for (int k = 0; k < 32; ++k) {
            float4 a = row[k], b = se4[k];
            s4.x += a.x * b.x; s4.y += a.y * b.y; s4.z += a.z * b.z; s4.w += a.w * b.w;
        }
        c_lds[t] = s4.x + s4.y + s4.z + s4.w;
    }

    // stage tile 0 -> buf 0; issue tile-1 loads (held across barrier in regs)
    {
        const unsigned short* Eb0 = EbBase + (size_t)row_base * 128;
        uint4 a0 = *(const uint4*)(Eb0 + t * 8);
        uint4 a1 = *(const uint4*)(Eb0 + (t + 256) * 8);
        uint4 a2 = *(const uint4*)(Eb0 + (t + 512) * 8);
        uint4 a3 = *(const uint4*)(Eb0 + (t + 768) * 8);
        *(uint4*)&Elds[0][sr0 * 136 + sc0 * 8] = a0;
        *(uint4*)&Elds[0][sr1 * 136 + sc1 * 8] = a1;
        *(uint4*)&Elds[0][sr2 * 136 + sc2 * 8] = a2;
        *(uint4*)&Elds[0][sr3 * 136 + sc3 * 8] = a3;
    }
    uint4 sN0, sN1, sN2, sN3;
    {
        const unsigned short* Eb1 = EbBase + (size_t)(row_base + 64) * 128;
        sN0 = *(const uint4*)(Eb1 + t * 8);
        sN1 = *(const uint4*)(Eb1 + (t + 256) * 8);
        sN2 = *(const uint4*)(Eb1 + (t + 512) * 8);
        sN3 = *(const uint4*)(Eb1 + (t + 768) * 8);
    }
    __syncthreads();   // B_pro: buf0/c_lds visible

    float cjr[2][4];
#pragma unroll
    for (int jt = 0; jt < 2; ++jt)
#pragma unroll
        for (int reg = 0; reg < 4; ++reg)
            cjr[jt][reg] = c_lds[w * 32 + jt * 16 + q * 4 + reg];

    float z_lane = 0.f;
    float acc8[8] = {0.f, 0.f, 0.f, 0.f, 0.f, 0.f, 0.f, 0.f};

    for (int it = 0; it < 8; ++it) {
        int cur = it % 3;
        int pb = it & 1;
        int trow0 = row_base + it * 64;

        // write tile it+1 (regs loaded at it-1 / prologue -> full-iter latency slack)
        if (it < 7) {
            int wr = (it + 1) % 3;
            *(uint4*)&Elds[wr][sr0 * 136 + sc0 * 8] = sN0;
            *(uint4*)&Elds[wr][sr1 * 136 + sc1 * 8] = sN1;
            *(uint4*)&Elds[wr][sr2 * 136 + sc2 * 8] = sN2;
            *(uint4*)&Elds[wr][sr3 * 136 + sc3 * 8] = sN3;
        }
        // issue loads for tile it+2
        if (it < 6) {
            const unsigned short* EbN = EbBase + (size_t)(trow0 + 128) * 128;
            sN0 = *(const uint4*)(EbN + t * 8);
            sN1 = *(const uint4*)(EbN + (t + 256) * 8);
            sN2 = *(const uint4*)(EbN + (t + 512) * 8);
            sN3 = *(const uint4*)(EbN + (t + 768) * 8);
        }
        float4 sp4 = *(const float4*)&ws[WS_SP + trow0 + r0];
        // e for this lane's epilogue cols (broadcast scalar loads, consumed much later)
        float evr[4];
#pragma unroll
        for (int rt = 0; rt < 4; ++rt) evr[rt] = e_ws[trow0 + rt * 16 + cl];

        // per-rt: ds_read b-frags -> 16 MFMA -> epilogue -> pim write (16 acc regs live)
#pragma unroll
        for (int rt = 0; rt < 4; ++rt) {
            bf16x8 b[4];
#pragma unroll
            for (int kt = 0; kt < 4; ++kt)
                b[kt] = *(const bf16x8*)&Elds[cur][(rt * 16 + cl) * 136 + kt * 32 + q * 8];
            f32x4 a00 = {0.f,0.f,0.f,0.f}, a01 = {0.f,0.f,0.f,0.f};
            f32x4 a10 = {0.f,0.f,0.f,0.f}, a11 = {0.f,0.f,0.f,0.f};
#pragma unroll
            for (int kt = 0; kt < 4; ++kt) {
                a00 = __builtin_amdgcn_mfma_f32_16x16x32_bf16(aw[0][0][kt], b[kt], a00, 0, 0, 0);
                a01 = __builtin_amdgcn_mfma_f32_16x16x32_bf16(aw[0][1][kt], b[kt], a01, 0, 0, 0);
                a10 = __builtin_amdgcn_mfma_f32_16x16x32_bf16(aw[1][0][kt], b[kt], a10, 0, 0, 0);
                a11 = __builtin_amdgcn_mfma_f32_16x16x32_bf16(aw[1][1][kt], b[kt], a11, 0, 0, 0);
            }
            float e_v = evr[rt];
            float di_v = 1.0f / (Sv - e_v);
            float p = 0.f;
#pragma unroll
            for (int reg = 0; reg < 4; ++reg) {       // jt=0 first (order matches r9)
                float h = a00[reg] + b12r[0][reg] + (cjr[0][reg] - e_v * a01[reg]) * di_v;
                p = fmaf(wvr[0][reg], fmaxf(h, 0.f), p);
            }
#pragma unroll
            for (int reg = 0; reg < 4; ++reg) {       // then jt=1
                float h = a10[reg] + b12r[1][reg] + (cjr[1][reg] - e_v * a11[reg]) * di_v;
                p = fmaf(wvr[1][reg], fmaxf(h, 0.f), p);
            }
            p += __shfl_xor(p, 16);
            p += __shfl_xor(p, 32);
            if (lane < 16) pim2[(pb * 64 + rt * 16 + lane) * 4 + w] = p;
        }
        __syncthreads();   // B1: pim[pb] + Elds[(it+1)%3] visible; sole barrier this tile

        // wexp: 4 rows/lane; one float4 per row
        float we[4];
#pragma unroll
        for (int rr = 0; rr < 4; ++rr) {
            float4 P = *(const float4*)&pim2[(pb * 64 + r0 + rr) * 4];
            float pi = (P.x + P.y) + (P.z + P.w);
            float spv = (rr == 0) ? sp4.x : (rr == 1) ? sp4.y : (rr == 2) ? sp4.z : sp4.w;
            we[rr] = __expf(spv + bvc + pi);
            z_lane += we[rr];
        }
        if (cl == 0)
            *(float4*)&ws[WS_WEXP + trow0 + r0] = (float4){we[0], we[1], we[2], we[3]};

#pragma unroll
        for (int rr = 0; rr < 4; ++rr) {
            int r = r0 + rr;
            float wer = we[rr];
            uint4 u = *(const uint4*)&Elds[cur][r * 136 + cl * 8];
            acc8[0] += wer * bfbits(u.x << 16);
            acc8[1] += wer * bfbits(u.x & 0xffff0000u);
            acc8[2] += wer * bfbits(u.y << 16);
            acc8[3] += wer * bfbits(u.y & 0xffff0000u);
            acc8[4] += wer * bfbits(u.z << 16);
            acc8[5] += wer * bfbits(u.z & 0xffff0000u);
            acc8[6] += wer * bfbits(u.w << 16);
            acc8[7] += wer * bfbits(u.w & 0xffff0000u);
        }
        // no trailing barrier: triple-buffered Elds / dbuf pim keep next iter's writes
        // WAR-safe (separated from this iter's reads by the NEXT B1)
    }

    __syncthreads();   // all pim reads done -> arena reusable as gep/zw

    z_lane += __shfl_xor(z_lane, 16);
    z_lane += __shfl_xor(z_lane, 32);
    if (lane == 0) zw[w] = z_lane;

#pragma unroll
    for (int jj = 0; jj < 8; ++jj) {
        acc8[jj] += __shfl_xor(acc8[jj], 16);
        acc8[jj] += __shfl_xor(acc8[jj], 32);
    }
    if (lane < 16) {
        *(float4*)&gep_a[w * 128 + cl * 8] = (float4){acc8[0], acc8[1], acc8[2], acc8[3]};
        *(float4*)&gep_a[w * 128 + cl * 8 + 4] = (float4){acc8[4], acc8[5], acc8[6], acc8[7]};
    }
    __syncthreads();

    if (t < 128) {
        float tot = gep_a[t] + gep_a[128 + t] + gep_a[256 + t] + gep_a[384 + t];
        atomicAdd(&ws[WS_GEB + (blk & 31) * 128 + t], tot);
    }
    if (t == 128) {
        float zs = zw[0] + zw[1] + zw[2] + zw[3];
        atomicAdd(&ws[WS_ZB + (blk & 63)], zs);
    }
}

// ---------------- K5: normalize + write outputs ----------------
__global__ __launch_bounds__(256) void k5_final(const float* __restrict__ ws,
                                                float* __restrict__ out) {
    int t = threadIdx.x, blk = blockIdx.x;
    float z = ws[WS_ZB + (t & 63)];
    for (int off = 1; off < 64; off <<= 1) z += __shfl_xor(z, off);
    float invZ = 1.0f / z;
    if (blk < 1024) {
        int i = blk * 256 + t;
        out[128 + i] = ws[WS_WEXP + i] * invZ;
    } else if (t < 128) {
        float s = 0.f;
#pragma unroll
        for (int b = 0; b < 32; ++b) s += ws[WS_GEB + b * 128 + t];
        out[t] = s * invZ;
    }
}

extern "C" void kernel_launch(void* const* d_in, const int* in_sizes, int n_in,
                              void* d_out, int out_size, void* d_ws, size_t ws_size,
                              hipStream_t stream) {
    const float* E   = (const float*)d_in[0];
    const float* v   = (const float*)d_in[1];
    const float* Wc1 = (const float*)d_in[2];
    const float* bc1 = (const float*)d_in[3];
    const float* Wc2 = (const float*)d_in[4];
    const float* bc2 = (const float*)d_in[5];
    const float* wpa = (const float*)d_in[6];
    const float* bpa = (const float*)d_in[7];
    const float* wvc = (const float*)d_in[8];
    const float* bvc = (const float*)d_in[9];
    float* ws  = (float*)d_ws;
    float* out = (float*)d_out;

    k2_stats<<<1024, 256, 0, stream>>>(E, v, wpa, bpa, Wc1, Wc2, bc1, bc2, ws);
    k2b_reduce<<<129, 256, 0, stream>>>(ws);
    k4_main<<<512, 256, 0, stream>>>(wvc, bvc, Wc2, ws);
    k5_final<<<1025, 256, 0, stream>>>(ws, out);
}

// Round 12
// 247.946 us; speedup vs baseline: 1.0855x; 1.0140x over previous
//
#include <hip/hip_runtime.h>
#include <hip/hip_bf16.h>

#define DIM 128

typedef __attribute__((ext_vector_type(8))) short bf16x8;
typedef __attribute__((ext_vector_type(4))) float f32x4;

// ---- ws layout (float offsets) ----
#define WS_B12    0        // 128
#define WS_C      128      // 128  (unused; layout stability)
#define WS_SUMEE  256      // 128
#define WS_S      384      // 1
#define WS_ZB     416      // 64   Z buckets (atomic, 64-way)
#define WS_GEB    512      // 32*128 ge buckets (atomic, 32-way)
#define WS_WBF    4608     // 32768 bf16: Wcat[n][k]
#define WS_EEP    20992    // 128*1024 sum_eE partials
#define WS_SEP    152064   // 1024 S partials
#define WS_SP     153088   // N
#define WS_E      415232   // N
#define WS_WEXP   677376   // N
// (EBF copy removed in r12: k4 stages fp32 E directly — E is L3-resident after k2's
//  streaming read, and the bf16 conversion is done in-register with identical RNE bits.
//  Saves 64 MB of HBM writes in k2.)

__device__ __forceinline__ unsigned short f2bf(float f) {
    union { float f; unsigned u; } v; v.f = f;
    unsigned r = v.u + 0x7fffu + ((v.u >> 16) & 1u);
    return (unsigned short)(r >> 16);
}

__device__ __forceinline__ float bfbits(unsigned u) {
    union { unsigned u; float f; } v; v.u = u;
    return v.f;
}

// pack two f32 -> one u32 of 2x bf16 (RNE). Compiler emits v_cvt_pk_bf16_f32.
__device__ __forceinline__ unsigned pkbf(float a, float b) {
    union { __hip_bfloat162 h; unsigned u; } cv;
    cv.h = __float22bfloat162_rn(make_float2(a, b));
    return cv.u;
}

// ---------------- K2: one pass over E -> sp, e, per-block {S, sum_eE} partials ----------------
__global__ __launch_bounds__(256) void k2_stats(const float* __restrict__ E,
                                                const float* __restrict__ v,
                                                const float* __restrict__ wpa,
                                                const float* __restrict__ bpa,
                                                const float* __restrict__ Wc1,
                                                const float* __restrict__ Wc2,
                                                const float* __restrict__ bc1,
                                                const float* __restrict__ bc2,
                                                float* __restrict__ ws) {
    __shared__ float red[16][128];
    __shared__ float redS[16];
    int t = threadIdx.x;

    // ---- folded k1: weight conversion + bucket zero-init
    int gid = blockIdx.x * 256 + t;
    unsigned short* wbf_w = (unsigned short*)(ws + WS_WBF);
    if (gid < 32768) {
        int n = gid >> 7, k = gid & 127;
        float val = (n < 128) ? Wc1[n * 128 + k] : Wc2[(n - 128) * 128 + k];
        wbf_w[gid] = f2bf(val);
    }
    if (gid < 4096) ws[WS_GEB + gid] = 0.f;
    if (gid < 128) ws[WS_B12 + gid] = bc1[gid] + bc2[gid];
    if (gid < 64) ws[WS_ZB + gid] = 0.f;

    int wave = t >> 6, lane = t & 63;
    int cl = lane & 15, rs = lane >> 4;
    int row0 = blockIdx.x * 256;
    const float4* E4 = (const float4*)E;

    float4 va = ((const float4*)v)[cl];
    float4 vb = ((const float4*)v)[16 + cl];
    float4 pa = ((const float4*)wpa)[cl];
    float4 pb = ((const float4*)wpa)[16 + cl];
    float bias = bpa[0];

    float4 acc0 = {0.f, 0.f, 0.f, 0.f}, acc1 = {0.f, 0.f, 0.f, 0.f};
    float se = 0.f;
    float* sp_ws = ws + WS_SP;
    float* e_ws = ws + WS_E;

#pragma unroll 8
    for (int it = 0; it < 16; ++it) {
        int row = row0 + it * 16 + wave * 4 + rs;
        float4 x0 = E4[row * 32 + cl];
        float4 x1 = E4[row * 32 + 16 + cl];

        float dv = x0.x * va.x + x0.y * va.y + x0.z * va.z + x0.w * va.w
                 + x1.x * vb.x + x1.y * vb.y + x1.z * vb.z + x1.w * vb.w;
        float dp = x0.x * pa.x + x0.y * pa.y + x0.z * pa.z + x0.w * pa.w
                 + x1.x * pb.x + x1.y * pb.y + x1.z * pb.z + x1.w * pb.w;
        for (int off = 1; off < 16; off <<= 1) {
            dv += __shfl_xor(dv, off);
            dp += __shfl_xor(dp, off);
        }
        float e = __expf(dp + bias);
        if (cl == 0) {
            sp_ws[row] = dv;
            e_ws[row] = e;
            se += e;
        }
        acc0.x += e * x0.x; acc0.y += e * x0.y; acc0.z += e * x0.z; acc0.w += e * x0.w;
        acc1.x += e * x1.x; acc1.y += e * x1.y; acc1.z += e * x1.z; acc1.w += e * x1.w;
    }
    int rr = wave * 4 + rs;
    float* dst = red[rr];
    dst[cl * 4 + 0] = acc0.x; dst[cl * 4 + 1] = acc0.y;
    dst[cl * 4 + 2] = acc0.z; dst[cl * 4 + 3] = acc0.w;
    dst[64 + cl * 4 + 0] = acc1.x; dst[64 + cl * 4 + 1] = acc1.y;
    dst[64 + cl * 4 + 2] = acc1.z; dst[64 + cl * 4 + 3] = acc1.w;
    if (cl == 0) redS[rr] = se;
    __syncthreads();
    if (t < 128) {
        float s = 0.f;
#pragma unroll
        for (int r = 0; r < 16; ++r) s += red[r][t];
        ws[WS_EEP + t * 1024 + blockIdx.x] = s;
    }
    if (t == 0) {
        float s = 0.f;
#pragma unroll
        for (int r = 0; r < 16; ++r) s += redS[r];
        ws[WS_SEP + blockIdx.x] = s;
    }
}

// ---------------- K2b: reduce partials -> SUMEE[128], S ----------------
__global__ __launch_bounds__(256) void k2b_reduce(float* __restrict__ ws) {
    __shared__ float r4[4];
    int t = threadIdx.x, blk = blockIdx.x;
    const float* src = (blk < 128) ? (ws + WS_EEP + blk * 1024) : (ws + WS_SEP);
    float s = src[t] + src[t + 256] + src[t + 512] + src[t + 768];
    for (int off = 1; off < 64; off <<= 1) s += __shfl_xor(s, off);
    if ((t & 63) == 0) r4[t >> 6] = s;
    __syncthreads();
    if (t == 0) {
        float tot = r4[0] + r4[1] + r4[2] + r4[3];
        if (blk < 128) ws[WS_SUMEE + blk] = tot;
        else ws[WS_S] = tot;
    }
}

// ---------------- K4: 4-wave transposed MFMA GEMM, 8 tiles/block, 1 barrier/tile ----------------
// r11 structure (reg-staged, depth-2, per-rt accumulators) with the staged source now
// the ORIGINAL fp32 E (L3-resident after k2's read) + in-register RNE bf16 conversion
// at ds_write time (v_cvt_pk_bf16_f32 — identical bits to the old k2-written copy).
// Kills the 64 MB EBF HBM-write in k2. Staging regs 16->32 VGPR (peak ~206, still
// 2 blocks/CU at (256,2)); +16 cvt_pk/thread/tile (trivial VALU).
__global__ __launch_bounds__(256, 2) void k4_main(const float* __restrict__ E,
                                                  const float* __restrict__ wvc,
                                                  const float* __restrict__ bvc_p,
                                                  const float* __restrict__ Wc2,
                                                  float* __restrict__ ws) {
    __shared__ unsigned short Elds[3][64 * 136];   // 3 x 17,408 B
    __shared__ __align__(16) float arena[644];
    // loop-phase:  pim2 = arena[0..511] ([2][64][4]); c_lds = arena[512..639]
    // final-phase: gep  = arena[0..511] ([4][128]); zw = arena[640..643]
    float* pim2  = arena;
    float* c_lds = arena + 512;
    float* zw    = arena + 640;
    float* gep_a = arena;

    int t = threadIdx.x;
    int w = t >> 6, lane = t & 63, cl = lane & 15, q = lane >> 4;
    int blk = blockIdx.x;
    int row_base = blk * 512;                    // 8 tiles x 64 rows
    const unsigned short* wbf = (const unsigned short*)(ws + WS_WBF);
    const float* e_ws = ws + WS_E;

    float bvc = bvc_p[0];
    float Sv = ws[WS_S];
    int r0 = w * 16 + q * 4;                     // this lane's 4 rows within a tile
    int sr[4], sc[4];
#pragma unroll
    for (int k = 0; k < 4; ++k) { sr[k] = (t + k * 256) >> 4; sc[k] = (t + k * 256) & 15; }

    // A fragments: wave w owns j-tiles {2w, 2w+1} for BOTH W_c1 and W_c2
    bf16x8 aw[2][2][4];   // [jt][0=W1,1=W2][kt]
#pragma unroll
    for (int jt = 0; jt < 2; ++jt) {
#pragma unroll
        for (int kt = 0; kt < 4; ++kt) {
            int jrow = w * 32 + jt * 16 + cl;
            aw[jt][0][kt] = *(const bf16x8*)(wbf + jrow * 128 + kt * 32 + q * 8);
            aw[jt][1][kt] = *(const bf16x8*)(wbf + (128 + jrow) * 128 + kt * 32 + q * 8);
        }
    }

    // per-lane j-row constants: j = w*32 + jt*16 + q*4 + reg
    float b12r[2][4], wvr[2][4];
#pragma unroll
    for (int jt = 0; jt < 2; ++jt)
#pragma unroll
        for (int reg = 0; reg < 4; ++reg) {
            int jr = w * 32 + jt * 16 + q * 4 + reg;
            b12r[jt][reg] = ws[WS_B12 + jr];
            wvr[jt][reg] = wvc[jr];
        }

    // folded k3: c[j] = Wc2[j,:] . sumEE
    if (t < 128) {
        const float4* row = (const float4*)(Wc2 + t * 128);
        const float4* se4 = (const float4*)(ws + WS_SUMEE);
        float4 s4 = {0.f, 0.f, 0.f, 0.f};
#pragma unroll
        for (int k = 0; k < 32; ++k) {
            float4 a = row[k], b = se4[k];
            s4.x += a.x * b.x; s4.y += a.y * b.y; s4.z += a.z * b.z; s4.w += a.w * b.w;
        }
        c_lds[t] = s4.x + s4.y + s4.z + s4.w;
    }

    // stage tile 0 -> buf 0 (fp32 -> bf16 RNE in-register); issue tile-1 loads
    {
        const float* E0 = E + (size_t)row_base * 128;
#pragma unroll
        for (int k = 0; k < 4; ++k) {
            const float* p = E0 + sr[k] * 128 + sc[k] * 8;
            float4 f0 = *(const float4*)p;
            float4 f1 = *(const float4*)(p + 4);
            uint4 u;
            u.x = pkbf(f0.x, f0.y); u.y = pkbf(f0.z, f0.w);
            u.z = pkbf(f1.x, f1.y); u.w = pkbf(f1.z, f1.w);
            *(uint4*)&Elds[0][sr[k] * 136 + sc[k] * 8] = u;
        }
    }
    float4 sN[8];   // tile-(it+1) staged fp32 (held across barrier in regs)
    {
        const float* E1 = E + (size_t)(row_base + 64) * 128;
#pragma unroll
        for (int k = 0; k < 4; ++k) {
            const float* p = E1 + sr[k] * 128 + sc[k] * 8;
            sN[2 * k]     = *(const float4*)p;
            sN[2 * k + 1] = *(const float4*)(p + 4);
        }
    }
    __syncthreads();   // B_pro: buf0/c_lds visible

    float cjr[2][4];
#pragma unroll
    for (int jt = 0; jt < 2; ++jt)
#pragma unroll
        for (int reg = 0; reg < 4; ++reg)
            cjr[jt][reg] = c_lds[w * 32 + jt * 16 + q * 4 + reg];

    float z_lane = 0.f;
    float acc8[8] = {0.f, 0.f, 0.f, 0.f, 0.f, 0.f, 0.f, 0.f};

    for (int it = 0; it < 8; ++it) {
        int cur = it % 3;
        int pb = it & 1;
        int trow0 = row_base + it * 64;

        // write tile it+1 (regs loaded at it-1 / prologue -> full-iter latency slack)
        if (it < 7) {
            int wr = (it + 1) % 3;
#pragma unroll
            for (int k = 0; k < 4; ++k) {
                uint4 u;
                u.x = pkbf(sN[2 * k].x, sN[2 * k].y);
                u.y = pkbf(sN[2 * k].z, sN[2 * k].w);
                u.z = pkbf(sN[2 * k + 1].x, sN[2 * k + 1].y);
                u.w = pkbf(sN[2 * k + 1].z, sN[2 * k + 1].w);
                *(uint4*)&Elds[wr][sr[k] * 136 + sc[k] * 8] = u;
            }
        }
        // issue loads for tile it+2
        if (it < 6) {
            const float* EsN = E + (size_t)(trow0 + 128) * 128;
#pragma unroll
            for (int k = 0; k < 4; ++k) {
                const float* p = EsN + sr[k] * 128 + sc[k] * 8;
                sN[2 * k]     = *(const float4*)p;
                sN[2 * k + 1] = *(const float4*)(p + 4);
            }
        }
        float4 sp4 = *(const float4*)&ws[WS_SP + trow0 + r0];
        // e for this lane's epilogue cols (broadcast scalar loads, consumed much later)
        float evr[4];
#pragma unroll
        for (int rt = 0; rt < 4; ++rt) evr[rt] = e_ws[trow0 + rt * 16 + cl];

        // per-rt: ds_read b-frags -> 16 MFMA -> epilogue -> pim write (16 acc regs live)
#pragma unroll
        for (int rt = 0; rt < 4; ++rt) {
            bf16x8 b[4];
#pragma unroll
            for (int kt = 0; kt < 4; ++kt)
                b[kt] = *(const bf16x8*)&Elds[cur][(rt * 16 + cl) * 136 + kt * 32 + q * 8];
            f32x4 a00 = {0.f,0.f,0.f,0.f}, a01 = {0.f,0.f,0.f,0.f};
            f32x4 a10 = {0.f,0.f,0.f,0.f}, a11 = {0.f,0.f,0.f,0.f};
#pragma unroll
            for (int kt = 0; kt < 4; ++kt) {
                a00 = __builtin_amdgcn_mfma_f32_16x16x32_bf16(aw[0][0][kt], b[kt], a00, 0, 0, 0);
                a01 = __builtin_amdgcn_mfma_f32_16x16x32_bf16(aw[0][1][kt], b[kt], a01, 0, 0, 0);
                a10 = __builtin_amdgcn_mfma_f32_16x16x32_bf16(aw[1][0][kt], b[kt], a10, 0, 0, 0);
                a11 = __builtin_amdgcn_mfma_f32_16x16x32_bf16(aw[1][1][kt], b[kt], a11, 0, 0, 0);
            }
            float e_v = evr[rt];
            float di_v = 1.0f / (Sv - e_v);
            float p = 0.f;
#pragma unroll
            for (int reg = 0; reg < 4; ++reg) {       // jt=0 first (order matches r11)
                float h = a00[reg] + b12r[0][reg] + (cjr[0][reg] - e_v * a01[reg]) * di_v;
                p = fmaf(wvr[0][reg], fmaxf(h, 0.f), p);
            }
#pragma unroll
            for (int reg = 0; reg < 4; ++reg) {       // then jt=1
                float h = a10[reg] + b12r[1][reg] + (cjr[1][reg] - e_v * a11[reg]) * di_v;
                p = fmaf(wvr[1][reg], fmaxf(h, 0.f), p);
            }
            p += __shfl_xor(p, 16);
            p += __shfl_xor(p, 32);
            if (lane < 16) pim2[(pb * 64 + rt * 16 + lane) * 4 + w] = p;
        }
        __syncthreads();   // B1: pim[pb] + Elds[(it+1)%3] visible; sole barrier this tile

        // wexp: 4 rows/lane; one float4 per row
        float we[4];
#pragma unroll
        for (int rr = 0; rr < 4; ++rr) {
            float4 P = *(const float4*)&pim2[(pb * 64 + r0 + rr) * 4];
            float pi = (P.x + P.y) + (P.z + P.w);
            float spv = (rr == 0) ? sp4.x : (rr == 1) ? sp4.y : (rr == 2) ? sp4.z : sp4.w;
            we[rr] = __expf(spv + bvc + pi);
            z_lane += we[rr];
        }
        if (cl == 0)
            *(float4*)&ws[WS_WEXP + trow0 + r0] = (float4){we[0], we[1], we[2], we[3]};

#pragma unroll
        for (int rr = 0; rr < 4; ++rr) {
            int r = r0 + rr;
            float wer = we[rr];
            uint4 u = *(const uint4*)&Elds[cur][r * 136 + cl * 8];
            acc8[0] += wer * bfbits(u.x << 16);
            acc8[1] += wer * bfbits(u.x & 0xffff0000u);
            acc8[2] += wer * bfbits(u.y << 16);
            acc8[3] += wer * bfbits(u.y & 0xffff0000u);
            acc8[4] += wer * bfbits(u.z << 16);
            acc8[5] += wer * bfbits(u.z & 0xffff0000u);
            acc8[6] += wer * bfbits(u.w << 16);
            acc8[7] += wer * bfbits(u.w & 0xffff0000u);
        }
        // no trailing barrier: triple-buffered Elds / dbuf pim keep next iter's writes
        // WAR-safe (separated from this iter's reads by the NEXT B1)
    }

    __syncthreads();   // all pim reads done -> arena reusable as gep/zw

    z_lane += __shfl_xor(z_lane, 16);
    z_lane += __shfl_xor(z_lane, 32);
    if (lane == 0) zw[w] = z_lane;

#pragma unroll
    for (int jj = 0; jj < 8; ++jj) {
        acc8[jj] += __shfl_xor(acc8[jj], 16);
        acc8[jj] += __shfl_xor(acc8[jj], 32);
    }
    if (lane < 16) {
        *(float4*)&gep_a[w * 128 + cl * 8] = (float4){acc8[0], acc8[1], acc8[2], acc8[3]};
        *(float4*)&gep_a[w * 128 + cl * 8 + 4] = (float4){acc8[4], acc8[5], acc8[6], acc8[7]};
    }
    __syncthreads();

    if (t < 128) {
        float tot = gep_a[t] + gep_a[128 + t] + gep_a[256 + t] + gep_a[384 + t];
        atomicAdd(&ws[WS_GEB + (blk & 31) * 128 + t], tot);
    }
    if (t == 128) {
        float zs = zw[0] + zw[1] + zw[2] + zw[3];
        atomicAdd(&ws[WS_ZB + (blk & 63)], zs);
    }
}

// ---------------- K5: normalize + write outputs ----------------
__global__ __launch_bounds__(256) void k5_final(const float* __restrict__ ws,
                                                float* __restrict__ out) {
    int t = threadIdx.x, blk = blockIdx.x;
    float z = ws[WS_ZB + (t & 63)];
    for (int off = 1; off < 64; off <<= 1) z += __shfl_xor(z, off);
    float invZ = 1.0f / z;
    if (blk < 1024) {
        int i = blk * 256 + t;
        out[128 + i] = ws[WS_WEXP + i] * invZ;
    } else if (t < 128) {
        float s = 0.f;
#pragma unroll
        for (int b = 0; b < 32; ++b) s += ws[WS_GEB + b * 128 + t];
        out[t] = s * invZ;
    }
}

extern "C" void kernel_launch(void* const* d_in, const int* in_sizes, int n_in,
                              void* d_out, int out_size, void* d_ws, size_t ws_size,
                              hipStream_t stream) {
    const float* E   = (const float*)d_in[0];
    const float* v   = (const float*)d_in[1];
    const float* Wc1 = (const float*)d_in[2];
    const float* bc1 = (const float*)d_in[3];
    const float* Wc2 = (const float*)d_in[4];
    const float* bc2 = (const float*)d_in[5];
    const float* wpa = (const float*)d_in[6];
    const float* bpa = (const float*)d_in[7];
    const float* wvc = (const float*)d_in[8];
    const float* bvc = (const float*)d_in[9];
    float* ws  = (float*)d_ws;
    float* out = (float*)d_out;

    k2_stats<<<1024, 256, 0, stream>>>(E, v, wpa, bpa, Wc1, Wc2, bc1, bc2, ws);
    k2b_reduce<<<129, 256, 0, stream>>>(ws);
    k4_main<<<512, 256, 0, stream>>>(E, wvc, bvc, Wc2, ws);
    k5_final<<<1025, 256, 0, stream>>>(ws, out);
}